// Round 11
// baseline (102.823 us; speedup 1.0000x reference)
//
#include <hip/hip_runtime.h>
#include <math.h>

#define BB 2
#define CC 192
#define DI 384
#define SS 16
#define RR 12
#define KK 4

// ---------------- K1: one pass over x, float4; fixed-h/w-slot scheme ----------------
// grid = B*C, block = 256
__global__ void k_reduce(const float* __restrict__ x, float* __restrict__ seq) {
  int bc = blockIdx.x; int b = bc / CC, c = bc % CC;
  const float4* xin = (const float4*)(x + (size_t)bc * 32768);
  int t = threadIdx.x;
  int wid = t >> 6;
  __shared__ float pd[32][4];
  __shared__ float swa[256 * 4];
  float hacc = 0.f;
  float4 wacc = {0.f, 0.f, 0.f, 0.f};
  #pragma unroll 8
  for (int k = 0; k < 32; ++k) {
    float4 v = xin[k * 256 + t];
    float s = v.x + v.y + v.z + v.w;
    hacc += s;
    wacc.x += v.x; wacc.y += v.y; wacc.z += v.z; wacc.w += v.w;
    float ss = s;
    #pragma unroll
    for (int off = 32; off > 0; off >>= 1) ss += __shfl_down(ss, off, 64);
    if ((t & 63) == 0) pd[k][wid] = ss;
  }
  #pragma unroll
  for (int off = 4; off > 0; off >>= 1) hacc += __shfl_down(hacc, off, 8);
  if ((t & 7) == 0)
    seq[((1 * BB + b) * 32 + (t >> 3)) * CC + c] = hacc * (1.f / 1024.f);
  ((float4*)swa)[t] = wacc;
  __syncthreads();
  if (t < 32) {
    float s0 = pd[t][0] + pd[t][1] + pd[t][2] + pd[t][3];
    seq[((0 * BB + b) * 32 + t) * CC + c] = s0 * (1.f / 1024.f);
    float s2 = 0.f;
    #pragma unroll
    for (int m = 0; m < 32; ++m) s2 += swa[t + 32 * m];
    seq[((2 * BB + b) * 32 + t) * CC + c] = s2 * (1.f / 1024.f);
  }
}

// ---------------- K2: LN + in-proj(4 xm rows + own z) + conv+silu + xp, per token ----------------
// grid = 192, block = 384. Eliminates the separate in-proj kernel & xmz buffer.
__global__ void k_convall(const float* __restrict__ seq, const float* __restrict__ ln_w,
                          const float* __restrict__ ln_b, const float* __restrict__ in_w,
                          const float* __restrict__ conv_w, const float* __restrict__ conv_b,
                          const float* __restrict__ xp_w, float* __restrict__ xc,
                          float* __restrict__ zbuf, float* __restrict__ dbc) {
  int tok = blockIdx.x; int l = tok & 31; int tb = tok >> 5; int i = tb / BB;
  int t = threadIdx.x;
  __shared__ float sseq[4][CC];
  __shared__ float smu[4], sri[4];
  __shared__ float sxm[4][DI];
  __shared__ float xcl[DI];
  for (int j = t; j < 4 * CC; j += 384) {
    int k = j / CC, c = j - k * CC;
    int ls = l - 3 + k;
    sseq[k][c] = (ls >= 0) ? seq[(tb * 32 + ls) * CC + c] : 0.f;
  }
  __syncthreads();
  int wid = t >> 6, lane = t & 63;
  if (wid < 4) {
    float sm = 0.f, sq = 0.f;
    for (int e = lane; e < CC; e += 64) { float v = sseq[wid][e]; sm += v; sq += v * v; }
    #pragma unroll
    for (int off = 32; off > 0; off >>= 1) { sm += __shfl_down(sm, off, 64); sq += __shfl_down(sq, off, 64); }
    if (lane == 0) { float mu = sm / CC; smu[wid] = mu; sri[wid] = rsqrtf(sq / CC - mu * mu + 1e-5f); }
  }
  __syncthreads();
  for (int j = t; j < 4 * CC; j += 384) {
    int k = j / CC, c = j - k * CC;
    sseq[k][c] = (sseq[k][c] - smu[k]) * sri[k] * ln_w[i * CC + c] + ln_b[i * CC + c];
  }
  __syncthreads();
  {
    const float4* wr = (const float4*)(in_w + ((size_t)i * 768 + t) * CC);
    const float4* wz = (const float4*)(in_w + ((size_t)i * 768 + 384 + t) * CC);
    const float4* s0 = (const float4*)sseq[0];
    const float4* s1 = (const float4*)sseq[1];
    const float4* s2 = (const float4*)sseq[2];
    const float4* s3 = (const float4*)sseq[3];
    float a0 = 0.f, a1 = 0.f, a2 = 0.f, a3 = 0.f, az = 0.f;
    #pragma unroll 4
    for (int c4 = 0; c4 < CC / 4; ++c4) {
      float4 w = wr[c4];
      float4 q0 = s0[c4], q1 = s1[c4], q2 = s2[c4], q3 = s3[c4];
      a0 += w.x * q0.x + w.y * q0.y + w.z * q0.z + w.w * q0.w;
      a1 += w.x * q1.x + w.y * q1.y + w.z * q1.z + w.w * q1.w;
      a2 += w.x * q2.x + w.y * q2.y + w.z * q2.z + w.w * q2.w;
      a3 += w.x * q3.x + w.y * q3.y + w.z * q3.z + w.w * q3.w;
      float4 z = wz[c4];
      az += z.x * q3.x + z.y * q3.y + z.z * q3.z + z.w * q3.w;
    }
    int bl = l - 3;
    sxm[0][t] = (bl + 0 >= 0) ? a0 : 0.f;
    sxm[1][t] = (bl + 1 >= 0) ? a1 : 0.f;
    sxm[2][t] = (bl + 2 >= 0) ? a2 : 0.f;
    sxm[3][t] = a3;
    zbuf[(size_t)tok * DI + t] = az;
  }
  __syncthreads();
  {
    int di = t;
    const float* cw = conv_w + ((size_t)i * DI + di) * KK;
    float acc = conv_b[i * DI + di];
    #pragma unroll
    for (int k = 0; k < KK; ++k) acc += cw[k] * sxm[k][di];
    acc = acc / (1.f + expf(-acc));
    xcl[di] = acc;
    xc[(size_t)tok * DI + di] = acc;
  }
  __syncthreads();
  if (t < 352) {
    int o = t >> 3, ln8 = t & 7;
    const float4* wr = (const float4*)(xp_w + ((size_t)i * 44 + o) * DI);
    const float4* xv = (const float4*)xcl;
    float acc = 0.f;
    #pragma unroll
    for (int c4 = ln8 * 12; c4 < ln8 * 12 + 12; ++c4) {
      float4 a = wr[c4], bq = xv[c4];
      acc += a.x * bq.x + a.y * bq.y + a.z * bq.z + a.w * bq.w;
    }
    #pragma unroll
    for (int off = 4; off > 0; off >>= 1) acc += __shfl_xor(acc, off, 8);
    if (ln8 == 0) dbc[tok * 44 + o] = acc;
  }
}

// ---------------- K3: scan (dt-proj+softplus inlined at staging) ----------------
// grid = 288 (6 ib x 48 chunks), block = 128 (8 di x 16 s)
__global__ void k_scan(const float* __restrict__ dbc, const float* __restrict__ xc,
                       const float* __restrict__ zbuf, const float* __restrict__ dt_w,
                       const float* __restrict__ dt_b, const float* __restrict__ A_log,
                       const float* __restrict__ Dskip, float* __restrict__ y,
                       float* __restrict__ ymean) {
  int ib = blockIdx.x / 48;
  int di0 = (blockIdx.x % 48) * 8;
  int i = ib / BB;
  int t = threadIdx.x;
  int g = t >> 4, s = t & 15;
  int di = di0 + g;
  __shared__ float sdt[32][8], sxc[32][8], sz[32][8];
  __shared__ float sB[32][SS], sC[32][SS];
  __shared__ float spp[32 * 136];
  __shared__ float sy[32][8];
  __shared__ float sDsk[8];
  #pragma unroll
  for (int j = t; j < 256; j += 128) {
    int l = j >> 3, gg = j & 7;
    int tok = ib * 32 + l;
    sxc[l][gg] = xc[(size_t)tok * DI + di0 + gg];
    sz[l][gg]  = zbuf[(size_t)tok * DI + di0 + gg];
    const float* wr = dt_w + ((size_t)i * DI + di0 + gg) * RR;
    float acc = dt_b[i * DI + di0 + gg];
    #pragma unroll
    for (int r = 0; r < RR; ++r) acc += wr[r] * dbc[tok * 44 + r];
    sdt[l][gg] = (acc > 20.f) ? acc : log1pf(expf(acc));
  }
  #pragma unroll
  for (int j = t; j < 512; j += 128) {
    int l = j >> 4, ss = j & 15;
    sB[l][ss] = dbc[(ib * 32 + l) * 44 + RR + ss];
    sC[l][ss] = dbc[(ib * 32 + l) * 44 + RR + SS + ss];
  }
  if (t < 8) sDsk[t] = Dskip[i * DI + di0 + t];
  float A = -expf(A_log[((size_t)i * DI + di) * SS + s]);
  float h = 0.f;
  __syncthreads();
  #pragma unroll
  for (int l = 0; l < 32; ++l) {
    float dtt = sdt[l][g];
    h = expf(dtt * A) * h + dtt * sxc[l][g] * sB[l][s];
    spp[l * 136 + g * 17 + s] = h * sC[l][s];
  }
  __syncthreads();
  #pragma unroll
  for (int p = 0; p < 2; ++p) {
    int idx = p * 128 + t;
    int l = idx >> 3, g2 = idx & 7;
    float sum = 0.f;
    #pragma unroll
    for (int s2 = 0; s2 < 16; ++s2) sum += spp[l * 136 + g2 * 17 + s2];
    float xt = sxc[l][g2];
    float z  = sz[l][g2];
    float yv = (sum + sDsk[g2] * xt) * (z / (1.f + expf(-z)));
    y[(size_t)(ib * 32 + l) * DI + di0 + g2] = yv;
    sy[l][g2] = yv;
  }
  __syncthreads();
  if (t < 8) {
    float sum = 0.f;
    #pragma unroll
    for (int l = 0; l < 32; ++l) sum += sy[l][t];
    ymean[ib * DI + di0 + t] = sum * (1.f / 32.f);
  }
}

// ---------------- K4: mz = up_b + up_w @ (out_w @ {y[tok] | ymean}) ; 4-way split ----------------
// grid = 198, block = 768
__global__ void k_mz(const float* __restrict__ y, const float* __restrict__ ymean,
                     const float* __restrict__ out_w, const float* __restrict__ up_w,
                     const float* __restrict__ up_b, float* __restrict__ zrow) {
  int j = blockIdx.x;
  int t = threadIdx.x;
  __shared__ float src[DI];
  __shared__ float pa[768];
  __shared__ float mrowL[CC];
  int i = (j < 192) ? (j >> 6) : (j - 192) / BB;
  if (t < DI) src[t] = (j < 192) ? y[(size_t)j * DI + t] : ymean[(j - 192) * DI + t];
  __syncthreads();
  int o = t >> 2, qr = t & 3;
  {
    const float4* wr = (const float4*)(out_w + ((size_t)i * CC + o) * DI);
    const float4* sv = (const float4*)src;
    float acc = 0.f;
    #pragma unroll 8
    for (int c4 = qr * 24; c4 < qr * 24 + 24; ++c4) {
      float4 a = wr[c4], bq = sv[c4];
      acc += a.x * bq.x + a.y * bq.y + a.z * bq.z + a.w * bq.w;
    }
    pa[t] = acc;
  }
  __syncthreads();
  if (t < 192) {
    float4 pv = ((const float4*)pa)[t];
    mrowL[t] = pv.x + pv.y + pv.z + pv.w;
  }
  __syncthreads();
  {
    const float4* ur = (const float4*)(up_w + ((size_t)i * CC + o) * CC);
    const float4* mv = (const float4*)mrowL;
    float acc = 0.f;
    #pragma unroll 8
    for (int c4 = qr * 12; c4 < qr * 12 + 12; ++c4) {
      float4 a = ur[c4], bq = mv[c4];
      acc += a.x * bq.x + a.y * bq.y + a.z * bq.z + a.w * bq.w;
    }
    pa[t] = acc;
  }
  __syncthreads();
  if (t < 192) {
    float4 pv = ((const float4*)pa)[t];
    zrow[(size_t)j * CC + t] = up_b[i * CC + t] + pv.x + pv.y + pv.z + pv.w;
  }
}

// ---------------- K5: gate per token, 4-way split dots ----------------
// grid = 192, block = 768
__global__ void k_gate(const float* __restrict__ zrow, const float* __restrict__ Wg_w,
                       const float* __restrict__ Wg_b, const float* __restrict__ Ws_w,
                       const float* __restrict__ Ws_b, const float* __restrict__ Wm_w,
                       const float* __restrict__ Wm_b, const float* __restrict__ po_w,
                       float* __restrict__ P) {
  int blk = blockIdx.x; int gb = blk >> 5; int g = gb / BB, b = gb - g * BB;
  int o1 = (g == 0) ? 1 : 0, o2 = (g == 2) ? 1 : 2;
  int t = threadIdx.x;
  __shared__ float zr[CC], zm0[CC], zm1[CC], arow[CC], ygr[CC];
  __shared__ float pa[768], pb[768];
  if (t < CC)            zr[t]        = zrow[(size_t)blk * CC + t];
  else if (t < 2 * CC)   zm0[t - CC]  = zrow[(size_t)(192 + o1 * BB + b) * CC + (t - CC)];
  else if (t < 3 * CC)   zm1[t - 2*CC]= zrow[(size_t)(192 + o2 * BB + b) * CC + (t - 2*CC)];
  __syncthreads();
  int o = t >> 2, qr = t & 3;
  {
    const float4* wr = (const float4*)(Ws_w + (size_t)o * CC);
    const float4* zv = (const float4*)zr;
    float acc = 0.f;
    #pragma unroll 4
    for (int c4 = qr * 12; c4 < qr * 12 + 12; ++c4) {
      float4 a = wr[c4], bq = zv[c4];
      acc += a.x * bq.x + a.y * bq.y + a.z * bq.z + a.w * bq.w;
    }
    pa[t] = acc;
    const float4* gwr = (const float4*)(Wg_w + (size_t)o * 2 * CC);
    float acc2 = 0.f;
    #pragma unroll 4
    for (int c4 = qr * 24; c4 < qr * 24 + 24; ++c4) {
      float4 a = gwr[c4];
      float4 bq = (c4 < 48) ? ((const float4*)zm0)[c4] : ((const float4*)zm1)[c4 - 48];
      acc2 += a.x * bq.x + a.y * bq.y + a.z * bq.z + a.w * bq.w;
    }
    pb[t] = acc2;
  }
  __syncthreads();
  if (t < 192) {
    float4 sa = ((const float4*)pa)[t];
    float4 sb = ((const float4*)pb)[t];
    float a = (Ws_b[t] + sa.x + sa.y + sa.z + sa.w) + (Wg_b[t] + sb.x + sb.y + sb.z + sb.w);
    arow[t] = a > 0.f ? a : 0.f;
  }
  __syncthreads();
  {
    const float4* mr = (const float4*)(Wm_w + (size_t)o * CC);
    const float4* av = (const float4*)arow;
    float acc = 0.f;
    #pragma unroll 4
    for (int c4 = qr * 12; c4 < qr * 12 + 12; ++c4) {
      float4 a = mr[c4], bq = av[c4];
      acc += a.x * bq.x + a.y * bq.y + a.z * bq.z + a.w * bq.w;
    }
    pa[t] = acc;
  }
  __syncthreads();
  if (t < 192) {
    float4 sa = ((const float4*)pa)[t];
    float am = Wm_b[t] + sa.x + sa.y + sa.z + sa.w;
    am = 1.f / (1.f + expf(-am));
    ygr[t] = am * zr[t];
  }
  __syncthreads();
  {
    const float4* pr = (const float4*)(po_w + (size_t)o * (3 * CC) + g * CC);
    const float4* yv = (const float4*)ygr;
    float acc = 0.f;
    #pragma unroll 4
    for (int c4 = qr * 12; c4 < qr * 12 + 12; ++c4) {
      float4 a = pr[c4], bq = yv[c4];
      acc += a.x * bq.x + a.y * bq.y + a.z * bq.z + a.w * bq.w;
    }
    pb[t] = acc;
  }
  __syncthreads();
  if (t < 192) {
    float4 sb = ((const float4*)pb)[t];
    P[(size_t)blk * CC + t] = sb.x + sb.y + sb.z + sb.w;
  }
}

// ---------------- K6: final: warp-parallel separable stats + broadcast + residual ----------------
// grid = B*C*2, block = 256
__global__ void k_final(const float* __restrict__ x, const float* __restrict__ P,
                        const float* __restrict__ po_b, const float* __restrict__ rs_p,
                        float* __restrict__ out) {
  int bc = blockIdx.x >> 1; int half = blockIdx.x & 1;
  int b = bc / CC, c = bc % CC;
  __shared__ float p0[32], p1[32], p2[32];
  __shared__ float sbase;
  int t = threadIdx.x;
  if (t < 32) {
    float v0 = P[((0 * BB + b) * 32 + t) * CC + c];
    float v1 = P[((1 * BB + b) * 32 + t) * CC + c];
    float v2 = P[((2 * BB + b) * 32 + t) * CC + c];
    float s0 = v0, q0 = v0 * v0, s1 = v1, q1 = v1 * v1, s2 = v2, q2 = v2 * v2;
    #pragma unroll
    for (int off = 16; off > 0; off >>= 1) {
      s0 += __shfl_xor(s0, off, 32); q0 += __shfl_xor(q0, off, 32);
      s1 += __shfl_xor(s1, off, 32); q1 += __shfl_xor(q1, off, 32);
      s2 += __shfl_xor(s2, off, 32); q2 += __shfl_xor(q2, off, 32);
    }
    float m0 = s0 * (1.f / 32.f), m1 = s1 * (1.f / 32.f), m2 = s2 * (1.f / 32.f);
    float var = (q0 * (1.f / 32.f) - m0 * m0) + (q1 * (1.f / 32.f) - m1 * m1) + (q2 * (1.f / 32.f) - m2 * m2);
    float mu = po_b[c] + m0 + m1 + m2;
    float sc = rs_p[0] * rsqrtf(var + 1e-5f);
    p0[t] = v0 * sc; p1[t] = v1 * sc; p2[t] = v2 * sc;
    if (t == 0) sbase = sc * (po_b[c] - mu);
  }
  __syncthreads();
  float basev = sbase;
  const float4* xin = (const float4*)(x + (size_t)bc * 32768);
  float4* xo = (float4*)(out + (size_t)bc * 32768);
  const float4* p2v = (const float4*)p2;
  int q0i = half * 4096;
  #pragma unroll 4
  for (int q = q0i + t; q < q0i + 4096; q += 256) {
    int d = q >> 8, h = (q >> 3) & 31;
    float add = basev + p0[d] + p1[h];
    float4 pw = p2v[q & 7];
    float4 v = xin[q];
    v.x += add + pw.x;
    v.y += add + pw.y;
    v.z += add + pw.z;
    v.w += add + pw.w;
    xo[q] = v;
  }
}

extern "C" void kernel_launch(void* const* d_in, const int* in_sizes, int n_in,
                              void* d_out, int out_size, void* d_ws, size_t ws_size,
                              hipStream_t stream) {
  const float* x      = (const float*)d_in[0];
  const float* ln_w   = (const float*)d_in[1];
  const float* ln_b   = (const float*)d_in[2];
  const float* in_w   = (const float*)d_in[3];
  const float* conv_w = (const float*)d_in[4];
  const float* conv_b = (const float*)d_in[5];
  const float* xp_w   = (const float*)d_in[6];
  const float* dt_w   = (const float*)d_in[7];
  const float* dt_b   = (const float*)d_in[8];
  const float* A_log  = (const float*)d_in[9];
  const float* Dskip  = (const float*)d_in[10];
  const float* out_w  = (const float*)d_in[11];
  const float* up_w   = (const float*)d_in[12];
  const float* up_b   = (const float*)d_in[13];
  const float* Wg_w   = (const float*)d_in[14];
  const float* Wg_b   = (const float*)d_in[15];
  const float* Ws_w   = (const float*)d_in[16];
  const float* Ws_b   = (const float*)d_in[17];
  const float* Wm_w   = (const float*)d_in[18];
  const float* Wm_b   = (const float*)d_in[19];
  const float* po_w   = (const float*)d_in[20];
  const float* po_b   = (const float*)d_in[21];
  const float* rs_p   = (const float*)d_in[22];
  float* out = (float*)d_out;

  float* ws    = (float*)d_ws;
  float* seq   = ws;                 // 36864
  float* xc    = seq   + 36864;      // 73728
  float* zbuf  = xc    + 73728;      // 73728
  float* dbc   = zbuf  + 73728;      // 8448
  float* y     = dbc   + 8448;       // 73728
  float* ymean = y     + 73728;      // 2304
  float* zrow  = ymean + 2304;       // 38016
  float* P     = zrow  + 38016;      // 36864

  k_reduce <<<dim3(BB * CC),     dim3(256), 0, stream>>>(x, seq);
  k_convall<<<dim3(3 * BB * 32), dim3(384), 0, stream>>>(seq, ln_w, ln_b, in_w, conv_w, conv_b,
                                                         xp_w, xc, zbuf, dbc);
  k_scan   <<<dim3(288),         dim3(128), 0, stream>>>(dbc, xc, zbuf, dt_w, dt_b, A_log,
                                                         Dskip, y, ymean);
  k_mz     <<<dim3(198),         dim3(768), 0, stream>>>(y, ymean, out_w, up_w, up_b, zrow);
  k_gate   <<<dim3(192),         dim3(768), 0, stream>>>(zrow, Wg_w, Wg_b, Ws_w, Ws_b,
                                                         Wm_w, Wm_b, po_w, P);
  k_final  <<<dim3(BB * CC * 2), dim3(256), 0, stream>>>(x, P, po_b, rs_p, out);
}

// Round 12
// 84.180 us; speedup vs baseline: 1.2215x; 1.2215x over previous
//
#include <hip/hip_runtime.h>
#include <math.h>

#define BB 2
#define CC 192
#define DI 384
#define SS 16
#define RR 12
#define KK 4

// bf16 weight pool offsets (ushort units)
#define N_IN  442368
#define N_XP  50688
#define N_OUT 221184
#define N_UP  110592
#define N_WG  73728
#define N_WS  36864
#define N_WM  36864
#define N_PO  110592
#define O_IN  0
#define O_XP  442368
#define O_OUT 493056
#define O_UP  714240
#define O_WG  824832
#define O_WS  898560
#define O_WM  935424
#define O_PO  972288

__device__ __forceinline__ unsigned short f2bf(float f) {
  unsigned int u = __float_as_uint(f);
  u += 0x7FFFu + ((u >> 16) & 1u);          // round-to-nearest-even
  return (unsigned short)(u >> 16);
}

// dot of 8 bf16 weights (packed in uint4) with 8 fp32 activations (2 float4s at a2)
__device__ __forceinline__ float dot8(uint4 w, const float4* a2) {
  float4 a0 = a2[0], a1 = a2[1];
  float s;
  s  = __uint_as_float(w.x << 16) * a0.x + __uint_as_float(w.x & 0xFFFF0000u) * a0.y;
  s += __uint_as_float(w.y << 16) * a0.z + __uint_as_float(w.y & 0xFFFF0000u) * a0.w;
  s += __uint_as_float(w.z << 16) * a1.x + __uint_as_float(w.z & 0xFFFF0000u) * a1.y;
  s += __uint_as_float(w.w << 16) * a1.z + __uint_as_float(w.w & 0xFFFF0000u) * a1.w;
  return s;
}

// ---------------- K1: x-pass reductions + bf16 weight conversion (piggybacked) ----------------
// grid = B*C, block = 256
__global__ void k_reduce(const float* __restrict__ x, float* __restrict__ seq,
                         const float* __restrict__ in_w, const float* __restrict__ xp_w,
                         const float* __restrict__ out_w, const float* __restrict__ up_w,
                         const float* __restrict__ Wg_w, const float* __restrict__ Ws_w,
                         const float* __restrict__ Wm_w, const float* __restrict__ po_w,
                         unsigned short* __restrict__ ub) {
  int bc = blockIdx.x; int b = bc / CC, c = bc % CC;
  const float4* xin = (const float4*)(x + (size_t)bc * 32768);
  int t = threadIdx.x;
  int wid = t >> 6;
  __shared__ float pd[32][4];
  __shared__ float swa[256 * 4];
  float hacc = 0.f;
  float4 wacc = {0.f, 0.f, 0.f, 0.f};
  #pragma unroll 8
  for (int k = 0; k < 32; ++k) {
    float4 v = xin[k * 256 + t];
    float s = v.x + v.y + v.z + v.w;
    hacc += s;
    wacc.x += v.x; wacc.y += v.y; wacc.z += v.z; wacc.w += v.w;
    float ss = s;
    #pragma unroll
    for (int off = 32; off > 0; off >>= 1) ss += __shfl_down(ss, off, 64);
    if ((t & 63) == 0) pd[k][wid] = ss;
  }
  #pragma unroll
  for (int off = 4; off > 0; off >>= 1) hacc += __shfl_down(hacc, off, 8);
  if ((t & 7) == 0)
    seq[((1 * BB + b) * 32 + (t >> 3)) * CC + c] = hacc * (1.f / 1024.f);
  ((float4*)swa)[t] = wacc;
  __syncthreads();
  if (t < 32) {
    float s0 = pd[t][0] + pd[t][1] + pd[t][2] + pd[t][3];
    seq[((0 * BB + b) * 32 + t) * CC + c] = s0 * (1.f / 1024.f);
    float s2 = 0.f;
    #pragma unroll
    for (int m = 0; m < 32; ++m) s2 += swa[t + 32 * m];
    seq[((2 * BB + b) * 32 + t) * CC + c] = s2 * (1.f / 1024.f);
  }
  // ---- bf16 weight conversion (independent of the reduce work) ----
  size_t gid = (size_t)bc * 256 + t;
  const size_t stride = (size_t)BB * CC * 256;
  for (size_t e = gid; e < N_IN;  e += stride) ub[O_IN  + e] = f2bf(in_w[e]);
  for (size_t e = gid; e < N_XP;  e += stride) ub[O_XP  + e] = f2bf(xp_w[e]);
  for (size_t e = gid; e < N_OUT; e += stride) ub[O_OUT + e] = f2bf(out_w[e]);
  for (size_t e = gid; e < N_UP;  e += stride) ub[O_UP  + e] = f2bf(up_w[e]);
  for (size_t e = gid; e < N_WG;  e += stride) ub[O_WG  + e] = f2bf(Wg_w[e]);
  for (size_t e = gid; e < N_WS;  e += stride) ub[O_WS  + e] = f2bf(Ws_w[e]);
  for (size_t e = gid; e < N_WM;  e += stride) ub[O_WM  + e] = f2bf(Wm_w[e]);
  for (size_t e = gid; e < N_PO;  e += stride) ub[O_PO  + e] = f2bf(po_w[e]);
}

// ---------------- K2: LN + in-proj (bf16 weights); 1536 blocks x 192, XCD swizzle ----------------
__global__ void k_lninproj(const float* __restrict__ seq, const float* __restrict__ ln_w,
                           const float* __restrict__ ln_b, const unsigned short* __restrict__ ub,
                           float* __restrict__ xmz) {
  int orig = (blockIdx.x & 7) * 192 + (blockIdx.x >> 3);
  int tok = orig >> 3, chunk = orig & 7;
  int i = tok >> 6;
  int t = threadIdx.x;
  __shared__ float srow[CC];
  __shared__ float sw[3], qw[3];
  __shared__ float pa[192];
  float v = seq[tok * CC + t];
  float s = v, q = v * v;
  #pragma unroll
  for (int off = 32; off > 0; off >>= 1) { s += __shfl_down(s, off, 64); q += __shfl_down(q, off, 64); }
  if ((t & 63) == 0) { sw[t >> 6] = s; qw[t >> 6] = q; }
  __syncthreads();
  float S = sw[0] + sw[1] + sw[2];
  float Q = qw[0] + qw[1] + qw[2];
  float mu = S / CC;
  float var = Q / CC - mu * mu;
  srow[t] = (v - mu) * rsqrtf(var + 1e-5f) * ln_w[i * CC + t] + ln_b[i * CC + t];
  __syncthreads();
  int o = t >> 1, half = t & 1;
  int j = chunk * 96 + o;
  const uint4* wr = (const uint4*)(ub + O_IN + ((size_t)i * 768 + j) * CC);
  const float4* sr = (const float4*)srow;
  float acc = 0.f;
  #pragma unroll
  for (int u = half * 12; u < half * 12 + 12; ++u) acc += dot8(wr[u], sr + u * 2);
  pa[t] = acc;
  __syncthreads();
  if ((t & 1) == 0) xmz[(size_t)tok * 768 + j] = pa[t] + pa[t + 1];
}

// ---------------- K3: conv+silu + xp-proj (bf16), per token ----------------
// grid = 192, block = 384
__global__ void k_convxp(const float* __restrict__ xmz, const float* __restrict__ conv_w,
                         const float* __restrict__ conv_b, const unsigned short* __restrict__ ub,
                         float* __restrict__ xc, float* __restrict__ dbc) {
  int tok = blockIdx.x; int l = tok & 31; int tb = tok >> 5; int i = tb / BB;
  int t = threadIdx.x;
  __shared__ float xcl[DI];
  {
    int di = t;
    const float* cw = conv_w + ((size_t)i * DI + di) * KK;
    float acc = conv_b[i * DI + di];
    #pragma unroll
    for (int k = 0; k < KK; ++k) {
      int ls = l + k - 3;
      if (ls >= 0) acc += cw[k] * xmz[(size_t)(tb * 32 + ls) * 768 + di];
    }
    acc = acc / (1.f + expf(-acc));
    xcl[di] = acc;
    xc[(size_t)tok * DI + di] = acc;
  }
  __syncthreads();
  if (t < 352) {
    int o = t >> 3, ln8 = t & 7;
    const uint4* wr = (const uint4*)(ub + O_XP + ((size_t)i * 44 + o) * DI);
    const float4* xv = (const float4*)xcl;
    float acc = 0.f;
    #pragma unroll
    for (int u = ln8 * 6; u < ln8 * 6 + 6; ++u) acc += dot8(wr[u], xv + u * 2);
    #pragma unroll
    for (int off = 4; off > 0; off >>= 1) acc += __shfl_xor(acc, off, 8);
    if (ln8 == 0) dbc[tok * 44 + o] = acc;
  }
}

// ---------------- K4: scan (dt-proj+softplus inlined, fp32 dt_w) ----------------
// grid = 288 (6 ib x 48 chunks), block = 128 (8 di x 16 s)
__global__ void k_scan(const float* __restrict__ dbc, const float* __restrict__ xc,
                       const float* __restrict__ xmz, const float* __restrict__ dt_w,
                       const float* __restrict__ dt_b, const float* __restrict__ A_log,
                       const float* __restrict__ Dskip, float* __restrict__ y,
                       float* __restrict__ ymean) {
  int ib = blockIdx.x / 48;
  int di0 = (blockIdx.x % 48) * 8;
  int i = ib / BB;
  int t = threadIdx.x;
  int g = t >> 4, s = t & 15;
  int di = di0 + g;
  __shared__ float sdt[32][8], sxc[32][8], sz[32][8];
  __shared__ float sB[32][SS], sC[32][SS];
  __shared__ float spp[32 * 136];
  __shared__ float sy[32][8];
  __shared__ float sDsk[8];
  #pragma unroll
  for (int j = t; j < 256; j += 128) {
    int l = j >> 3, gg = j & 7;
    int tok = ib * 32 + l;
    sxc[l][gg] = xc[(size_t)tok * DI + di0 + gg];
    sz[l][gg]  = xmz[(size_t)tok * 768 + DI + di0 + gg];
    const float* wr = dt_w + ((size_t)i * DI + di0 + gg) * RR;
    float acc = dt_b[i * DI + di0 + gg];
    #pragma unroll
    for (int r = 0; r < RR; ++r) acc += wr[r] * dbc[tok * 44 + r];
    sdt[l][gg] = (acc > 20.f) ? acc : log1pf(expf(acc));
  }
  #pragma unroll
  for (int j = t; j < 512; j += 128) {
    int l = j >> 4, ss = j & 15;
    sB[l][ss] = dbc[(ib * 32 + l) * 44 + RR + ss];
    sC[l][ss] = dbc[(ib * 32 + l) * 44 + RR + SS + ss];
  }
  if (t < 8) sDsk[t] = Dskip[i * DI + di0 + t];
  float A = -expf(A_log[((size_t)i * DI + di) * SS + s]);
  float h = 0.f;
  __syncthreads();
  #pragma unroll
  for (int l = 0; l < 32; ++l) {
    float dtt = sdt[l][g];
    h = expf(dtt * A) * h + dtt * sxc[l][g] * sB[l][s];
    spp[l * 136 + g * 17 + s] = h * sC[l][s];
  }
  __syncthreads();
  #pragma unroll
  for (int p = 0; p < 2; ++p) {
    int idx = p * 128 + t;
    int l = idx >> 3, g2 = idx & 7;
    float sum = 0.f;
    #pragma unroll
    for (int s2 = 0; s2 < 16; ++s2) sum += spp[l * 136 + g2 * 17 + s2];
    float xt = sxc[l][g2];
    float z  = sz[l][g2];
    float yv = (sum + sDsk[g2] * xt) * (z / (1.f + expf(-z)));
    y[(size_t)(ib * 32 + l) * DI + di0 + g2] = yv;
    sy[l][g2] = yv;
  }
  __syncthreads();
  if (t < 8) {
    float sum = 0.f;
    #pragma unroll
    for (int l = 0; l < 32; ++l) sum += sy[l][t];
    ymean[ib * DI + di0 + t] = sum * (1.f / 32.f);
  }
}

// ---------------- K5: mz = up_b + up_w@(out_w@{y|ymean}) (bf16 weights); 4-way split ----------------
// grid = 198, block = 768
__global__ void k_mz(const float* __restrict__ y, const float* __restrict__ ymean,
                     const unsigned short* __restrict__ ub, const float* __restrict__ up_b,
                     float* __restrict__ zrow) {
  int j = blockIdx.x;
  int t = threadIdx.x;
  __shared__ float src[DI];
  __shared__ float pa[768];
  __shared__ float mrowL[CC];
  int i = (j < 192) ? (j >> 6) : (j - 192) / BB;
  if (t < DI) src[t] = (j < 192) ? y[(size_t)j * DI + t] : ymean[(j - 192) * DI + t];
  __syncthreads();
  int o = t >> 2, qr = t & 3;
  {
    const uint4* wr = (const uint4*)(ub + O_OUT + ((size_t)i * CC + o) * DI);
    const float4* sv = (const float4*)src;
    float acc = 0.f;
    #pragma unroll
    for (int u = qr * 12; u < qr * 12 + 12; ++u) acc += dot8(wr[u], sv + u * 2);
    pa[t] = acc;
  }
  __syncthreads();
  if (t < 192) {
    float4 pv = ((const float4*)pa)[t];
    mrowL[t] = pv.x + pv.y + pv.z + pv.w;
  }
  __syncthreads();
  {
    const uint4* ur = (const uint4*)(ub + O_UP + ((size_t)i * CC + o) * CC);
    const float4* mv = (const float4*)mrowL;
    float acc = 0.f;
    #pragma unroll
    for (int u = qr * 6; u < qr * 6 + 6; ++u) acc += dot8(ur[u], mv + u * 2);
    pa[t] = acc;
  }
  __syncthreads();
  if (t < 192) {
    float4 pv = ((const float4*)pa)[t];
    zrow[(size_t)j * CC + t] = up_b[i * CC + t] + pv.x + pv.y + pv.z + pv.w;
  }
}

// ---------------- K6: gate per token (bf16 weights), 4-way split dots ----------------
// grid = 192, block = 768
__global__ void k_gate(const float* __restrict__ zrow, const unsigned short* __restrict__ ub,
                       const float* __restrict__ Wg_b, const float* __restrict__ Ws_b,
                       const float* __restrict__ Wm_b, float* __restrict__ P) {
  int blk = blockIdx.x; int gb = blk >> 5; int g = gb / BB, b = gb - g * BB;
  int o1 = (g == 0) ? 1 : 0, o2 = (g == 2) ? 1 : 2;
  int t = threadIdx.x;
  __shared__ float zr[CC], zm0[CC], zm1[CC], arow[CC], ygr[CC];
  __shared__ float pa[768], pb[768];
  if (t < CC)            zr[t]         = zrow[(size_t)blk * CC + t];
  else if (t < 2 * CC)   zm0[t - CC]   = zrow[(size_t)(192 + o1 * BB + b) * CC + (t - CC)];
  else if (t < 3 * CC)   zm1[t - 2*CC] = zrow[(size_t)(192 + o2 * BB + b) * CC + (t - 2*CC)];
  __syncthreads();
  int o = t >> 2, qr = t & 3;
  {
    const uint4* wr = (const uint4*)(ub + O_WS + (size_t)o * CC);
    const float4* zv = (const float4*)zr;
    float acc = 0.f;
    #pragma unroll
    for (int u = qr * 6; u < qr * 6 + 6; ++u) acc += dot8(wr[u], zv + u * 2);
    pa[t] = acc;
    const uint4* gwr = (const uint4*)(ub + O_WG + (size_t)o * 2 * CC);
    float acc2 = 0.f;
    #pragma unroll
    for (int u = qr * 12; u < qr * 12 + 12; ++u) {
      const float4* av = (u < 24) ? ((const float4*)zm0 + u * 2) : ((const float4*)zm1 + (u - 24) * 2);
      acc2 += dot8(gwr[u], av);
    }
    pb[t] = acc2;
  }
  __syncthreads();
  if (t < 192) {
    float4 sa = ((const float4*)pa)[t];
    float4 sb = ((const float4*)pb)[t];
    float a = (Ws_b[t] + sa.x + sa.y + sa.z + sa.w) + (Wg_b[t] + sb.x + sb.y + sb.z + sb.w);
    arow[t] = a > 0.f ? a : 0.f;
  }
  __syncthreads();
  {
    const uint4* mr = (const uint4*)(ub + O_WM + (size_t)o * CC);
    const float4* av = (const float4*)arow;
    float acc = 0.f;
    #pragma unroll
    for (int u = qr * 6; u < qr * 6 + 6; ++u) acc += dot8(mr[u], av + u * 2);
    pa[t] = acc;
  }
  __syncthreads();
  if (t < 192) {
    float4 sa = ((const float4*)pa)[t];
    float am = Wm_b[t] + sa.x + sa.y + sa.z + sa.w;
    am = 1.f / (1.f + expf(-am));
    ygr[t] = am * zr[t];
  }
  __syncthreads();
  {
    const uint4* pr = (const uint4*)(ub + O_PO + (size_t)o * (3 * CC) + (size_t)g * CC);
    const float4* yv = (const float4*)ygr;
    float acc = 0.f;
    #pragma unroll
    for (int u = qr * 6; u < qr * 6 + 6; ++u) acc += dot8(pr[u], yv + u * 2);
    pb[t] = acc;
  }
  __syncthreads();
  if (t < 192) {
    float4 sb = ((const float4*)pb)[t];
    P[(size_t)blk * CC + t] = sb.x + sb.y + sb.z + sb.w;
  }
}

// ---------------- K7: final: warp-parallel separable stats + broadcast + residual ----------------
// grid = B*C*2, block = 256
__global__ void k_final(const float* __restrict__ x, const float* __restrict__ P,
                        const float* __restrict__ po_b, const float* __restrict__ rs_p,
                        float* __restrict__ out) {
  int bc = blockIdx.x >> 1; int half = blockIdx.x & 1;
  int b = bc / CC, c = bc % CC;
  __shared__ float p0[32], p1[32], p2[32];
  __shared__ float sbase;
  int t = threadIdx.x;
  if (t < 32) {
    float v0 = P[((0 * BB + b) * 32 + t) * CC + c];
    float v1 = P[((1 * BB + b) * 32 + t) * CC + c];
    float v2 = P[((2 * BB + b) * 32 + t) * CC + c];
    float s0 = v0, q0 = v0 * v0, s1 = v1, q1 = v1 * v1, s2 = v2, q2 = v2 * v2;
    #pragma unroll
    for (int off = 16; off > 0; off >>= 1) {
      s0 += __shfl_xor(s0, off, 32); q0 += __shfl_xor(q0, off, 32);
      s1 += __shfl_xor(s1, off, 32); q1 += __shfl_xor(q1, off, 32);
      s2 += __shfl_xor(s2, off, 32); q2 += __shfl_xor(q2, off, 32);
    }
    float m0 = s0 * (1.f / 32.f), m1 = s1 * (1.f / 32.f), m2 = s2 * (1.f / 32.f);
    float var = (q0 * (1.f / 32.f) - m0 * m0) + (q1 * (1.f / 32.f) - m1 * m1) + (q2 * (1.f / 32.f) - m2 * m2);
    float mu = po_b[c] + m0 + m1 + m2;
    float sc = rs_p[0] * rsqrtf(var + 1e-5f);
    p0[t] = v0 * sc; p1[t] = v1 * sc; p2[t] = v2 * sc;
    if (t == 0) sbase = sc * (po_b[c] - mu);
  }
  __syncthreads();
  float basev = sbase;
  const float4* xin = (const float4*)(x + (size_t)bc * 32768);
  float4* xo = (float4*)(out + (size_t)bc * 32768);
  const float4* p2v = (const float4*)p2;
  int q0i = half * 4096;
  #pragma unroll 4
  for (int q = q0i + t; q < q0i + 4096; q += 256) {
    int d = q >> 8, h = (q >> 3) & 31;
    float add = basev + p0[d] + p1[h];
    float4 pw = p2v[q & 7];
    float4 v = xin[q];
    v.x += add + pw.x;
    v.y += add + pw.y;
    v.z += add + pw.z;
    v.w += add + pw.w;
    xo[q] = v;
  }
}

extern "C" void kernel_launch(void* const* d_in, const int* in_sizes, int n_in,
                              void* d_out, int out_size, void* d_ws, size_t ws_size,
                              hipStream_t stream) {
  const float* x      = (const float*)d_in[0];
  const float* ln_w   = (const float*)d_in[1];
  const float* ln_b   = (const float*)d_in[2];
  const float* in_w   = (const float*)d_in[3];
  const float* conv_w = (const float*)d_in[4];
  const float* conv_b = (const float*)d_in[5];
  const float* xp_w   = (const float*)d_in[6];
  const float* dt_w   = (const float*)d_in[7];
  const float* dt_b   = (const float*)d_in[8];
  const float* A_log  = (const float*)d_in[9];
  const float* Dskip  = (const float*)d_in[10];
  const float* out_w  = (const float*)d_in[11];
  const float* up_w   = (const float*)d_in[12];
  const float* up_b   = (const float*)d_in[13];
  const float* Wg_w   = (const float*)d_in[14];
  const float* Wg_b   = (const float*)d_in[15];
  const float* Ws_w   = (const float*)d_in[16];
  const float* Ws_b   = (const float*)d_in[17];
  const float* Wm_w   = (const float*)d_in[18];
  const float* Wm_b   = (const float*)d_in[19];
  const float* po_w   = (const float*)d_in[20];
  const float* po_b   = (const float*)d_in[21];
  const float* rs_p   = (const float*)d_in[22];
  float* out = (float*)d_out;

  float* ws    = (float*)d_ws;
  float* seq   = ws;                 // 36864
  float* xmz   = seq   + 36864;      // 147456
  float* xc    = xmz   + 147456;     // 73728
  float* dbc   = xc    + 73728;      // 8448
  float* y     = dbc   + 8448;       // 73728
  float* ymean = y     + 73728;      // 2304
  float* zrow  = ymean + 2304;       // 38016
  float* P     = zrow  + 38016;      // 36864  (ends at float 417408)
  unsigned short* ub = (unsigned short*)(ws + 417408);   // 2.17 MB bf16 weight pool

  k_reduce  <<<dim3(BB * CC),     dim3(256), 0, stream>>>(x, seq, in_w, xp_w, out_w, up_w,
                                                          Wg_w, Ws_w, Wm_w, po_w, ub);
  k_lninproj<<<dim3(1536),        dim3(192), 0, stream>>>(seq, ln_w, ln_b, ub, xmz);
  k_convxp  <<<dim3(192),         dim3(384), 0, stream>>>(xmz, conv_w, conv_b, ub, xc, dbc);
  k_scan    <<<dim3(288),         dim3(128), 0, stream>>>(dbc, xc, xmz, dt_w, dt_b, A_log,
                                                          Dskip, y, ymean);
  k_mz      <<<dim3(198),         dim3(768), 0, stream>>>(y, ymean, ub, up_b, zrow);
  k_gate    <<<dim3(192),         dim3(768), 0, stream>>>(zrow, ub, Wg_b, Ws_b, Wm_b, P);
  k_final   <<<dim3(BB * CC * 2), dim3(256), 0, stream>>>(x, P, po_b, rs_p, out);
}